// Round 1
// baseline (76.015 us; speedup 1.0000x reference)
//
#include <hip/hip_runtime.h>

#define NT 8
#define ND 16
#define NH 16
#define NW 16
#define NC 32
#define NB 65536

// strides in float4 units (C=32 -> 8 float4 per control point)
#define SW 8
#define SH (NW * SW)        // 128
#define SD (NH * SH)        // 2048
#define ST (ND * SD)        // 32768

// Per-dim setup: continuous index, cubic B-spline weights, and the
// linear-extrapolation padding FOLDED into the 4 weights so all reads stay
// inside the unpadded grid. idx[] returned pre-multiplied by STRIDE.
template <int N, int STRIDE>
__device__ __forceinline__ void dim_setup(float u, int idx[4], float w[4]) {
    float s = u * (float)(N - 1);
    float fi = floorf(s);
    fi = fminf(fmaxf(fi, 0.0f), (float)(N - 2));
    float t = s - fi;
    int i = (int)fi;
    float t2 = t * t, t3 = t2 * t;
    const float c6 = 1.0f / 6.0f;
    float w0 = (1.0f - 3.0f * t + 3.0f * t2 - t3) * c6;
    float w1 = (4.0f - 6.0f * t2 + 3.0f * t3) * c6;
    float w2 = (1.0f + 3.0f * t + 3.0f * t2 - 3.0f * t3) * c6;
    float w3 = t3 * c6;
    int i0, i1, i2, i3;
    float v0, v1, v2, v3;
    if (i == 0) {
        // phantom point at -1 is 2*g0 - g1
        i0 = 0; i1 = 1; i2 = 2; i3 = 2;
        v0 = w1 + 2.0f * w0; v1 = w2 - w0; v2 = w3; v3 = 0.0f;
    } else if (i == N - 2) {
        // phantom point at N is 2*g[N-1] - g[N-2]
        i0 = N - 3; i1 = N - 2; i2 = N - 1; i3 = N - 1;
        v0 = w0; v1 = w1 - w3; v2 = w2 + 2.0f * w3; v3 = 0.0f;
    } else {
        i0 = i - 1; i1 = i; i2 = i + 1; i3 = i + 2;
        v0 = w0; v1 = w1; v2 = w2; v3 = w3;
    }
    idx[0] = i0 * STRIDE; idx[1] = i1 * STRIDE;
    idx[2] = i2 * STRIDE; idx[3] = i3 * STRIDE;
    w[0] = v0; w[1] = v1; w[2] = v2; w[3] = v3;
}

// 8 threads per query; thread handles channels [4s, 4s+4) as one float4.
// The 8 lanes of a query read contiguous 128B per control point -> coalesced.
__global__ __launch_bounds__(256, 4) void spline4d_kernel(
    const float* __restrict__ u, const float4* __restrict__ grid,
    float4* __restrict__ out) {
    int tid = blockIdx.x * blockDim.x + threadIdx.x;
    int q = tid >> 3;   // query index
    int s = tid & 7;    // float4 channel slice

    float4 uu = reinterpret_cast<const float4*>(u)[q];

    int it[4], id[4], ih[4], iw[4];
    float wt[4], wd[4], wh[4], ww[4];
    dim_setup<NT, ST>(uu.x, it, wt);
    dim_setup<ND, SD>(uu.y, id, wd);
    dim_setup<NH, SH>(uu.z, ih, wh);
    dim_setup<NW, SW>(uu.w, iw, ww);

    float4 acc = make_float4(0.0f, 0.0f, 0.0f, 0.0f);

#pragma unroll
    for (int i = 0; i < 4; ++i) {
        int offt = it[i];
        float wti = wt[i];
#pragma unroll
        for (int j = 0; j < 4; ++j) {
            int offtd = offt + id[j];
            float wij = wti * wd[j];
#pragma unroll
            for (int k = 0; k < 4; ++k) {
                int offtdh = offtd + ih[k] + s;
                float wijk = wij * wh[k];
#pragma unroll
                for (int l = 0; l < 4; ++l) {
                    float4 p = grid[offtdh + iw[l]];
                    float wgt = wijk * ww[l];
                    acc.x = fmaf(wgt, p.x, acc.x);
                    acc.y = fmaf(wgt, p.y, acc.y);
                    acc.z = fmaf(wgt, p.z, acc.z);
                    acc.w = fmaf(wgt, p.w, acc.w);
                }
            }
        }
    }

    out[q * 8 + s] = acc;
}

extern "C" void kernel_launch(void* const* d_in, const int* in_sizes, int n_in,
                              void* d_out, int out_size, void* d_ws, size_t ws_size,
                              hipStream_t stream) {
    const float* u = (const float*)d_in[0];
    const float4* grid = (const float4*)d_in[1];
    float4* out = (float4*)d_out;

    // 8 threads per query, 256 threads per block -> 32 queries per block
    int total_threads = NB * 8;
    int block = 256;
    int nblocks = total_threads / block;  // 2048
    spline4d_kernel<<<nblocks, block, 0, stream>>>(u, grid, out);
}

// Round 3
// 69.756 us; speedup vs baseline: 1.0897x; 1.0897x over previous
//
#include <hip/hip_runtime.h>

#define NT 8
#define ND 16
#define NH 16
#define NW 16
#define NC 32
#define NB 65536

// strides in "point-slice" units. fp16 path: one point = 32ch * 2B = 64B = 8 half4.
// f32 path: one point = 128B = 8 float4. Same index space for both.
#define SW 8
#define SH (NW * SW)        // 128
#define SD (NH * SH)        // 2048
#define ST (ND * SD)        // 32768

typedef __attribute__((ext_vector_type(4))) _Float16 half4;

// Per-dim setup with linear-extrapolation padding folded into the weights so
// all reads stay inside the unpadded grid. idx[] pre-multiplied by STRIDE.
template <int N, int STRIDE>
__device__ __forceinline__ void dim_setup(float u, int idx[4], float w[4]) {
    float s = u * (float)(N - 1);
    float fi = floorf(s);
    fi = fminf(fmaxf(fi, 0.0f), (float)(N - 2));
    float t = s - fi;
    int i = (int)fi;
    float t2 = t * t, t3 = t2 * t;
    const float c6 = 1.0f / 6.0f;
    float w0 = (1.0f - 3.0f * t + 3.0f * t2 - t3) * c6;
    float w1 = (4.0f - 6.0f * t2 + 3.0f * t3) * c6;
    float w2 = (1.0f + 3.0f * t + 3.0f * t2 - 3.0f * t3) * c6;
    float w3 = t3 * c6;
    int i0, i1, i2, i3;
    float v0, v1, v2, v3;
    if (i == 0) {
        i0 = 0; i1 = 1; i2 = 2; i3 = 2;
        v0 = w1 + 2.0f * w0; v1 = w2 - w0; v2 = w3; v3 = 0.0f;
    } else if (i == N - 2) {
        i0 = N - 3; i1 = N - 2; i2 = N - 1; i3 = N - 1;
        v0 = w0; v1 = w1 - w3; v2 = w2 + 2.0f * w3; v3 = 0.0f;
    } else {
        i0 = i - 1; i1 = i; i2 = i + 1; i3 = i + 2;
        v0 = w0; v1 = w1; v2 = w2; v3 = w3;
    }
    idx[0] = i0 * STRIDE; idx[1] = i1 * STRIDE;
    idx[2] = i2 * STRIDE; idx[3] = i3 * STRIDE;
    w[0] = v0; w[1] = v1; w[2] = v2; w[3] = v3;
}

// f32 grid (4 MiB) -> fp16 grid (2 MiB) in workspace, RNE.
__global__ __launch_bounds__(256) void convert_fp16_kernel(
    const float4* __restrict__ g, half4* __restrict__ hg) {
    int i = blockIdx.x * blockDim.x + threadIdx.x;
    float4 v = g[i];
    half4 h;
    h[0] = (_Float16)v.x;
    h[1] = (_Float16)v.y;
    h[2] = (_Float16)v.z;
    h[3] = (_Float16)v.w;
    hg[i] = h;
}

// 8 threads per query; thread s handles channels [4s, 4s+4).
// fp16 path: each lane gathers 8B (half4); the 8 lanes of a query cover one
// point's contiguous 64B.
__global__ __launch_bounds__(256, 4) void spline4d_fp16_kernel(
    const float* __restrict__ u, const half4* __restrict__ grid,
    float4* __restrict__ out) {
    int tid = blockIdx.x * blockDim.x + threadIdx.x;
    int q = tid >> 3;
    int s = tid & 7;

    float4 uu = reinterpret_cast<const float4*>(u)[q];

    int it[4], id[4], ih[4], iw[4];
    float wt[4], wd[4], wh[4], ww[4];
    dim_setup<NT, ST>(uu.x, it, wt);
    dim_setup<ND, SD>(uu.y, id, wd);
    dim_setup<NH, SH>(uu.z, ih, wh);
    dim_setup<NW, SW>(uu.w, iw, ww);

    float4 acc = make_float4(0.0f, 0.0f, 0.0f, 0.0f);

#pragma unroll
    for (int i = 0; i < 4; ++i) {
        int offt = it[i];
        float wti = wt[i];
#pragma unroll
        for (int j = 0; j < 4; ++j) {
            int offtd = offt + id[j];
            float wij = wti * wd[j];
#pragma unroll
            for (int k = 0; k < 4; ++k) {
                int offtdh = offtd + ih[k] + s;
                float wijk = wij * wh[k];
#pragma unroll
                for (int l = 0; l < 4; ++l) {
                    half4 p = grid[offtdh + iw[l]];
                    float wgt = wijk * ww[l];
                    acc.x = fmaf((float)p[0], wgt, acc.x);
                    acc.y = fmaf((float)p[1], wgt, acc.y);
                    acc.z = fmaf((float)p[2], wgt, acc.z);
                    acc.w = fmaf((float)p[3], wgt, acc.w);
                }
            }
        }
    }

    out[q * 8 + s] = acc;
}

// Fallback (workspace too small): original f32 gather kernel.
__global__ __launch_bounds__(256, 4) void spline4d_f32_kernel(
    const float* __restrict__ u, const float4* __restrict__ grid,
    float4* __restrict__ out) {
    int tid = blockIdx.x * blockDim.x + threadIdx.x;
    int q = tid >> 3;
    int s = tid & 7;

    float4 uu = reinterpret_cast<const float4*>(u)[q];

    int it[4], id[4], ih[4], iw[4];
    float wt[4], wd[4], wh[4], ww[4];
    dim_setup<NT, ST>(uu.x, it, wt);
    dim_setup<ND, SD>(uu.y, id, wd);
    dim_setup<NH, SH>(uu.z, ih, wh);
    dim_setup<NW, SW>(uu.w, iw, ww);

    float4 acc = make_float4(0.0f, 0.0f, 0.0f, 0.0f);

#pragma unroll
    for (int i = 0; i < 4; ++i) {
        int offt = it[i];
        float wti = wt[i];
#pragma unroll
        for (int j = 0; j < 4; ++j) {
            int offtd = offt + id[j];
            float wij = wti * wd[j];
#pragma unroll
            for (int k = 0; k < 4; ++k) {
                int offtdh = offtd + ih[k] + s;
                float wijk = wij * wh[k];
#pragma unroll
                for (int l = 0; l < 4; ++l) {
                    float4 p = grid[offtdh + iw[l]];
                    float wgt = wijk * ww[l];
                    acc.x = fmaf(wgt, p.x, acc.x);
                    acc.y = fmaf(wgt, p.y, acc.y);
                    acc.z = fmaf(wgt, p.z, acc.z);
                    acc.w = fmaf(wgt, p.w, acc.w);
                }
            }
        }
    }

    out[q * 8 + s] = acc;
}

extern "C" void kernel_launch(void* const* d_in, const int* in_sizes, int n_in,
                              void* d_out, int out_size, void* d_ws, size_t ws_size,
                              hipStream_t stream) {
    const float* u = (const float*)d_in[0];
    const float* grid_f32 = (const float*)d_in[1];
    float4* out = (float4*)d_out;

    const size_t n_grid_floats = (size_t)NT * ND * NH * NW * NC;  // 1,048,576
    const size_t hg_bytes = n_grid_floats * 2;                    // 2 MiB

    int total_threads = NB * 8;
    int block = 256;
    int nblocks = total_threads / block;  // 2048

    if (ws_size >= hg_bytes) {
        half4* hgrid = (half4*)d_ws;
        int cvt_blocks = (int)(n_grid_floats / 4 / 256);  // 1024
        convert_fp16_kernel<<<cvt_blocks, 256, 0, stream>>>(
            (const float4*)grid_f32, hgrid);
        spline4d_fp16_kernel<<<nblocks, block, 0, stream>>>(u, hgrid, out);
    } else {
        spline4d_f32_kernel<<<nblocks, block, 0, stream>>>(
            u, (const float4*)grid_f32, out);
    }
}